// Round 21
// baseline (1146.470 us; speedup 1.0000x reference)
//
#include <hip/hip_runtime.h>

// ResidualVectorQuantizer — bit-exact vs harness np ref (VERIFIED R14, absmax 0):
//   rr/cc: pure sequential sum of rounded squares
//   dot (einsum SSE3): l_i = fl(m_i+m_{i+4}), dot = (l0+l1)+(l2+l3)
//   dist = fl(fl(rr+cc) - fl(2*dot)); argmin first-min strict <.
// R21 perf: R20 structure (k-pair, transposed LDS, lane-half split-K) with the
// arithmetic chain in INLINE-ASM v_pk_mul_f32/v_pk_add_f32 (VOP3P packed f32;
// IEEE per-component == scalar rounding). -2*dot via pk_mul by -2.0 (exact
// sign/pow2 scale) + one pk_add == verified single-rounded subtract.

#define TOKENS   262144      // B*T
#define D        8
#define K        1024
#define Q        8
#define LOSS_OFF 2097152
#define CODES_OFF 2097153

#define BLK      256
#define GRID     (TOKENS / BLK)   // 1024 blocks; each block owns 256 tokens

typedef float v2f __attribute__((ext_vector_type(2)));

__device__ __forceinline__ v2f pk_mul(v2f a, v2f b) {
  v2f r;
  asm("v_pk_mul_f32 %0, %1, %2" : "=v"(r) : "v"(a), "v"(b));
  return r;
}
__device__ __forceinline__ v2f pk_add(v2f a, v2f b) {
  v2f r;
  asm("v_pk_add_f32 %0, %1, %2" : "=v"(r) : "v"(a), "v"(b));
  return r;
}

// pure sequential sum of 8 (verified tree)
__device__ __forceinline__ float np_sum8_pureseq(const float* __restrict__ p) {
#pragma clang fp contract(off)
  float s = p[0];
  s = s + p[1]; s = s + p[2]; s = s + p[3]; s = s + p[4];
  s = s + p[5]; s = s + p[6]; s = s + p[7];
  return s;
}

// ---- prep: cc[q*K+k] = sum(c*c) pure-seq ----
__global__ __launch_bounds__(BLK) void rvq_prep(const float* __restrict__ cb,
                                                float* __restrict__ cc) {
#pragma clang fp contract(off)
  int i = blockIdx.x * BLK + threadIdx.x;   // [0, Q*K)
  const float* c = cb + i * D;
  float p[D];
#pragma unroll
  for (int d = 0; d < D; ++d) p[d] = c[d] * c[d];
  cc[i] = np_sum8_pureseq(p);
}

// ---- main ----
__global__ __launch_bounds__(BLK) void rvq_main(const float* __restrict__ x,
                                                const float* __restrict__ cb,
                                                const float* __restrict__ cct,
                                                float* __restrict__ out,
                                                double* __restrict__ partials) {
#pragma clang fp contract(off)
  __shared__ float sCT[D][K];   // 32 KiB TRANSPOSED codebook: sCT[d][k]
  __shared__ float sCC[K];      // 4 KiB ||c||^2
  const int tid  = threadIdx.x;
  const int wid  = tid >> 6;
  const int lane = tid & 63;
  const int half = lane >> 5;         // 0: k in [0,512), 1: [512,1024)
  const int sub  = lane & 31;
  const int t0 = blockIdx.x * 256 + wid * 64 + sub;   // token A
  const int t1 = t0 + 32;                             // token B
  const int kb = half * (K / 2);

  float rfA[D], rfB[D], qvA[D], qvB[D];
  {
    const float4* xa = (const float4*)(x + t0 * D);
    const float4* xb = (const float4*)(x + t1 * D);
    float4 a0 = xa[0], a1 = xa[1], b0 = xb[0], b1 = xb[1];
    rfA[0] = a0.x; rfA[1] = a0.y; rfA[2] = a0.z; rfA[3] = a0.w;
    rfA[4] = a1.x; rfA[5] = a1.y; rfA[6] = a1.z; rfA[7] = a1.w;
    rfB[0] = b0.x; rfB[1] = b0.y; rfB[2] = b0.z; rfB[3] = b0.w;
    rfB[4] = b1.x; rfB[5] = b1.y; rfB[6] = b1.z; rfB[7] = b1.w;
#pragma unroll
    for (int d = 0; d < D; ++d) { qvA[d] = 0.0f; qvB[d] = 0.0f; }
  }
  double lossAcc = 0.0;
  const v2f neg2 = (v2f){-2.0f, -2.0f};

  for (int q = 0; q < Q; ++q) {
    __syncthreads();
    {
      const float* cbq = cb + q * (K * D);
      float* flat = (float*)sCT;
      for (int i = tid; i < K * D; i += BLK)
        flat[i] = cbq[(i & (K - 1)) * D + (i >> 10)];   // sCT[d][k] = cb[k][d]
      const float* ccq = cct + q * K;
      for (int i = tid; i < K; i += BLK) sCC[i] = ccq[i];
    }
    __syncthreads();

    // rr = pure-seq sum of rounded squares (verified tree)
    float rrA, rrB;
    {
      float p[D];
#pragma unroll
      for (int d = 0; d < D; ++d) p[d] = rfA[d] * rfA[d];
      rrA = np_sum8_pureseq(p);
#pragma unroll
      for (int d = 0; d < D; ++d) p[d] = rfB[d] * rfB[d];
      rrB = np_sum8_pureseq(p);
    }
    v2f rrA2 = (v2f){rrA, rrA}, rrB2 = (v2f){rrB, rrB};
    v2f rf2A[D], rf2B[D];
#pragma unroll
    for (int d = 0; d < D; ++d) {
      rf2A[d] = (v2f){rfA[d], rfA[d]};
      rf2B[d] = (v2f){rfB[d], rfB[d]};
    }

    // half-scan in k-pairs, packed-f32 asm; verified tree per component
    float bestA = 3.402823466e+38f, bestB = 3.402823466e+38f;
    int ia = kb, ib = kb;
    const float* ccb = &sCC[kb];
#pragma unroll 4
    for (int kp = 0; kp < K / 4; ++kp) {
      const int k = kb + kp * 2;
      v2f cd[D];
#pragma unroll
      for (int d = 0; d < D; ++d)
        cd[d] = *(const v2f*)&sCT[d][k];       // ds_read_b64
      v2f cc2 = *(const v2f*)&ccb[kp * 2];

      // token A: m_d = fl(r_d*c_d); l_i = m_i+m_{i+4}; dot=(l0+l1)+(l2+l3)
      v2f a0 = pk_mul(rf2A[0], cd[0]), a1 = pk_mul(rf2A[1], cd[1]),
          a2 = pk_mul(rf2A[2], cd[2]), a3 = pk_mul(rf2A[3], cd[3]),
          a4 = pk_mul(rf2A[4], cd[4]), a5 = pk_mul(rf2A[5], cd[5]),
          a6 = pk_mul(rf2A[6], cd[6]), a7 = pk_mul(rf2A[7], cd[7]);
      v2f La0 = pk_add(a0, a4), La1 = pk_add(a1, a5),
          La2 = pk_add(a2, a6), La3 = pk_add(a3, a7);
      v2f dA = pk_add(pk_add(La0, La1), pk_add(La2, La3));
      v2f sA = pk_add(pk_add(rrA2, cc2), pk_mul(dA, neg2));
      if (sA.x < bestA) { bestA = sA.x; ia = k; }
      if (sA.y < bestA) { bestA = sA.y; ia = k + 1; }

      // token B
      v2f b0 = pk_mul(rf2B[0], cd[0]), b1 = pk_mul(rf2B[1], cd[1]),
          b2 = pk_mul(rf2B[2], cd[2]), b3 = pk_mul(rf2B[3], cd[3]),
          b4 = pk_mul(rf2B[4], cd[4]), b5 = pk_mul(rf2B[5], cd[5]),
          b6 = pk_mul(rf2B[6], cd[6]), b7 = pk_mul(rf2B[7], cd[7]);
      v2f Lb0 = pk_add(b0, b4), Lb1 = pk_add(b1, b5),
          Lb2 = pk_add(b2, b6), Lb3 = pk_add(b3, b7);
      v2f dB = pk_add(pk_add(Lb0, Lb1), pk_add(Lb2, Lb3));
      v2f sB = pk_add(pk_add(rrB2, cc2), pk_mul(dB, neg2));
      if (sB.x < bestB) { bestB = sB.x; ib = k; }
      if (sB.y < bestB) { bestB = sB.y; ib = k + 1; }
    }

    // combine halves: lo wins ties (== numpy first-min over full K)
    float obA = __shfl_xor(bestA, 32);
    float obB = __shfl_xor(bestB, 32);
    int   oiA = __shfl_xor(ia, 32);
    int   oiB = __shfl_xor(ib, 32);
    float loA = half ? obA : bestA,  hiA = half ? bestA : obA;
    int   liA = half ? oiA : ia,     hiiA = half ? ia : oiA;
    int idxA = (loA <= hiA) ? liA : hiiA;
    float loB = half ? obB : bestB,  hiB = half ? bestB : obB;
    int   liB = half ? oiB : ib,     hiiB = half ? ib : oiB;
    int idxB = (loB <= hiB) ? liB : hiiB;

    // f32 update chain (gather from transposed layout; both halves in sync)
#pragma unroll
    for (int d = 0; d < D; ++d) {
      float eA = sCT[d][idxA];
      qvA[d] = qvA[d] + eA;
      rfA[d] = rfA[d] - eA;
      float fA = rfA[d] - eA;
      float eB = sCT[d][idxB];
      qvB[d] = qvB[d] + eB;
      rfB[d] = rfB[d] - eB;
      float fB = rfB[d] - eB;
      if (!half) {
        lossAcc = fma((double)fA, (double)fA, lossAcc);
        lossAcc = fma((double)fB, (double)fB, lossAcc);
      }
    }
    if (!half) {
      out[CODES_OFF + q * TOKENS + t0] = (float)idxA;
      out[CODES_OFF + q * TOKENS + t1] = (float)idxB;
    }
  }

  // straight-through: out_q = f32(x + f32(q - x)) — half 0 writes
  if (!half) {
    const float4* xa = (const float4*)(x + t0 * D);
    const float4* xb = (const float4*)(x + t1 * D);
    float4 a0 = xa[0], a1 = xa[1], b0 = xb[0], b1 = xb[1];
    float xsA[D] = {a0.x, a0.y, a0.z, a0.w, a1.x, a1.y, a1.z, a1.w};
    float xsB[D] = {b0.x, b0.y, b0.z, b0.w, b1.x, b1.y, b1.z, b1.w};
    float oA[D], oB[D];
#pragma unroll
    for (int d = 0; d < D; ++d) {
      oA[d] = xsA[d] + (qvA[d] - xsA[d]);
      oB[d] = xsB[d] + (qvB[d] - xsB[d]);
    }
    float4 v;
    v.x = oA[0]; v.y = oA[1]; v.z = oA[2]; v.w = oA[3];
    ((float4*)(out + t0 * D))[0] = v;
    v.x = oA[4]; v.y = oA[5]; v.z = oA[6]; v.w = oA[7];
    ((float4*)(out + t0 * D))[1] = v;
    v.x = oB[0]; v.y = oB[1]; v.z = oB[2]; v.w = oB[3];
    ((float4*)(out + t1 * D))[0] = v;
    v.x = oB[4]; v.y = oB[5]; v.z = oB[6]; v.w = oB[7];
    ((float4*)(out + t1 * D))[1] = v;
  }

  // block loss reduction (half-1 lanes contribute 0)
  for (int off = 32; off; off >>= 1) lossAcc += __shfl_down(lossAcc, off);
  __syncthreads();
  double* red = (double*)sCT;
  if ((tid & 63) == 0) red[tid >> 6] = lossAcc;
  __syncthreads();
  if (tid == 0) partials[blockIdx.x] = red[0] + red[1] + red[2] + red[3];
}

// ---- finalize loss (GRID=1024 partials) ----
__global__ __launch_bounds__(BLK) void rvq_loss(const double* __restrict__ partials,
                                                float* __restrict__ out) {
  int tid = threadIdx.x;
  double s = partials[tid] + partials[tid + BLK] +
             partials[tid + 2 * BLK] + partials[tid + 3 * BLK];
  for (int off = 32; off; off >>= 1) s += __shfl_down(s, off);
  __shared__ double red[4];
  if ((tid & 63) == 0) red[tid >> 6] = s;
  __syncthreads();
  if (tid == 0)
    out[LOSS_OFF] = (float)((red[0] + red[1] + red[2] + red[3]) *
                            (0.25 / 2097152.0));
}

extern "C" void kernel_launch(void* const* d_in, const int* in_sizes, int n_in,
                              void* d_out, int out_size, void* d_ws, size_t ws_size,
                              hipStream_t stream) {
  const float* x  = (const float*)d_in[0];
  const float* cb = (const float*)d_in[1];
  float* out = (float*)d_out;
  double* partials = (double*)d_ws;          // GRID doubles (8 KiB)
  float* cc = (float*)(partials + GRID);     // Q*K floats (32 KiB)

  rvq_prep<<<(Q * K) / BLK, BLK, 0, stream>>>(cb, cc);
  rvq_main<<<GRID, BLK, 0, stream>>>(x, cb, cc, out, partials);
  rvq_loss<<<1, BLK, 0, stream>>>(partials, out);
}

// Round 22
// 992.890 us; speedup vs baseline: 1.1547x; 1.1547x over previous
//
#include <hip/hip_runtime.h>

// ResidualVectorQuantizer — bit-exact vs harness np ref (VERIFIED R14, absmax 0):
//   rr/cc: pure sequential sum of rounded squares
//   dot (einsum SSE3): l_i = fl(m_i+m_{i+4}), dot = (l0+l1)+(l2+l3)
//   dist = fl(fl(rr+cc) - fl(2*dot)); argmin first-min strict <.
// R22: revert R21 asm (pk-f32 has no f32 throughput on CDNA4; busy-time equal,
// scheduling worse). R20 structure + 4-k groups via ds_read_b128 on transposed
// LDS (halves LDS issue count), scalar f32 math, <=-ordered in-group tie tree
// (== numpy first-min). Lane-half split-K + verified combine kept.

#define TOKENS   262144      // B*T
#define D        8
#define K        1024
#define Q        8
#define LOSS_OFF 2097152
#define CODES_OFF 2097153

#define BLK      256
#define GRID     (TOKENS / BLK)   // 1024 blocks; each block owns 256 tokens

// pure sequential sum of 8 (verified tree)
__device__ __forceinline__ float np_sum8_pureseq(const float* __restrict__ p) {
#pragma clang fp contract(off)
  float s = p[0];
  s = s + p[1]; s = s + p[2]; s = s + p[3]; s = s + p[4];
  s = s + p[5]; s = s + p[6]; s = s + p[7];
  return s;
}

// ---- prep: cc[q*K+k] = sum(c*c) pure-seq ----
__global__ __launch_bounds__(BLK) void rvq_prep(const float* __restrict__ cb,
                                                float* __restrict__ cc) {
#pragma clang fp contract(off)
  int i = blockIdx.x * BLK + threadIdx.x;   // [0, Q*K)
  const float* c = cb + i * D;
  float p[D];
#pragma unroll
  for (int d = 0; d < D; ++d) p[d] = c[d] * c[d];
  cc[i] = np_sum8_pureseq(p);
}

// verified einsum-SSE3 distance for one (token,k): m_d=fl(r_d*c_d),
// l_i=m_i+m_{i+4}, dot=(l0+l1)+(l2+l3), s=fl(fl(rr+cc)-fl(2*dot))
#define DIST1(RF, RR, CX, CCX, OUT)                                       \
  {                                                                       \
    float m0 = RF[0] * cd0.CX, m1 = RF[1] * cd1.CX, m2 = RF[2] * cd2.CX,  \
          m3 = RF[3] * cd3.CX, m4 = RF[4] * cd4.CX, m5 = RF[5] * cd5.CX,  \
          m6 = RF[6] * cd6.CX, m7 = RF[7] * cd7.CX;                       \
    float l0 = m0 + m4, l1 = m1 + m5, l2 = m2 + m6, l3 = m3 + m7;         \
    float dot = (l0 + l1) + (l2 + l3);                                    \
    OUT = (RR + cc4.CCX) - 2.0f * dot;                                    \
  }

// ---- main ----
__global__ __launch_bounds__(BLK) void rvq_main(const float* __restrict__ x,
                                                const float* __restrict__ cb,
                                                const float* __restrict__ cct,
                                                float* __restrict__ out,
                                                double* __restrict__ partials) {
#pragma clang fp contract(off)
  __shared__ float sCT[D][K];   // 32 KiB TRANSPOSED codebook: sCT[d][k]
  __shared__ float sCC[K];      // 4 KiB ||c||^2
  const int tid  = threadIdx.x;
  const int wid  = tid >> 6;
  const int lane = tid & 63;
  const int half = lane >> 5;         // 0: k in [0,512), 1: [512,1024)
  const int sub  = lane & 31;
  const int t0 = blockIdx.x * 256 + wid * 64 + sub;   // token A
  const int t1 = t0 + 32;                             // token B
  const int kb = half * (K / 2);

  float rfA[D], rfB[D], qvA[D], qvB[D];
  {
    const float4* xa = (const float4*)(x + t0 * D);
    const float4* xb = (const float4*)(x + t1 * D);
    float4 a0 = xa[0], a1 = xa[1], b0 = xb[0], b1 = xb[1];
    rfA[0] = a0.x; rfA[1] = a0.y; rfA[2] = a0.z; rfA[3] = a0.w;
    rfA[4] = a1.x; rfA[5] = a1.y; rfA[6] = a1.z; rfA[7] = a1.w;
    rfB[0] = b0.x; rfB[1] = b0.y; rfB[2] = b0.z; rfB[3] = b0.w;
    rfB[4] = b1.x; rfB[5] = b1.y; rfB[6] = b1.z; rfB[7] = b1.w;
#pragma unroll
    for (int d = 0; d < D; ++d) { qvA[d] = 0.0f; qvB[d] = 0.0f; }
  }
  double lossAcc = 0.0;

  for (int q = 0; q < Q; ++q) {
    __syncthreads();
    {
      const float* cbq = cb + q * (K * D);
      float* flat = (float*)sCT;
      for (int i = tid; i < K * D; i += BLK)
        flat[i] = cbq[(i & (K - 1)) * D + (i >> 10)];   // sCT[d][k] = cb[k][d]
      const float* ccq = cct + q * K;
      for (int i = tid; i < K; i += BLK) sCC[i] = ccq[i];
    }
    __syncthreads();

    // rr = pure-seq sum of rounded squares (verified tree)
    float rrA, rrB;
    {
      float p[D];
#pragma unroll
      for (int d = 0; d < D; ++d) p[d] = rfA[d] * rfA[d];
      rrA = np_sum8_pureseq(p);
#pragma unroll
      for (int d = 0; d < D; ++d) p[d] = rfB[d] * rfB[d];
      rrB = np_sum8_pureseq(p);
    }

    // half-scan in 4-k groups (ds_read_b128), scalar verified tree per k.
    // In-group tie tree uses <= with lower-k on the left == numpy first-min;
    // cross-group update uses strict < (earlier k wins ties).
    float bestA = 3.402823466e+38f, bestB = 3.402823466e+38f;
    int ia = kb, ib = kb;
    const float* ccb = &sCC[kb];
    for (int g = 0; g < K / 8; ++g) {   // 128 groups of 4 k per half
      const int k = kb + g * 4;
      float4 cd0 = *(const float4*)&sCT[0][k];
      float4 cd1 = *(const float4*)&sCT[1][k];
      float4 cd2 = *(const float4*)&sCT[2][k];
      float4 cd3 = *(const float4*)&sCT[3][k];
      float4 cd4 = *(const float4*)&sCT[4][k];
      float4 cd5 = *(const float4*)&sCT[5][k];
      float4 cd6 = *(const float4*)&sCT[6][k];
      float4 cd7 = *(const float4*)&sCT[7][k];
      float4 cc4 = *(const float4*)&ccb[g * 4];

      // token A
      float sa0, sa1, sa2, sa3;
      DIST1(rfA, rrA, x, x, sa0)
      DIST1(rfA, rrA, y, y, sa1)
      DIST1(rfA, rrA, z, z, sa2)
      DIST1(rfA, rrA, w, w, sa3)
      {
        float v01 = (sa0 <= sa1) ? sa0 : sa1;
        int   i01 = (sa0 <= sa1) ? k : k + 1;
        float v23 = (sa2 <= sa3) ? sa2 : sa3;
        int   i23 = (sa2 <= sa3) ? k + 2 : k + 3;
        float vg = (v01 <= v23) ? v01 : v23;
        int   ig = (v01 <= v23) ? i01 : i23;
        if (vg < bestA) { bestA = vg; ia = ig; }
      }

      // token B
      float sb0, sb1, sb2, sb3;
      DIST1(rfB, rrB, x, x, sb0)
      DIST1(rfB, rrB, y, y, sb1)
      DIST1(rfB, rrB, z, z, sb2)
      DIST1(rfB, rrB, w, w, sb3)
      {
        float v01 = (sb0 <= sb1) ? sb0 : sb1;
        int   i01 = (sb0 <= sb1) ? k : k + 1;
        float v23 = (sb2 <= sb3) ? sb2 : sb3;
        int   i23 = (sb2 <= sb3) ? k + 2 : k + 3;
        float vg = (v01 <= v23) ? v01 : v23;
        int   ig = (v01 <= v23) ? i01 : i23;
        if (vg < bestB) { bestB = vg; ib = ig; }
      }
    }

    // combine halves: lo wins ties (== numpy first-min over full K)
    float obA = __shfl_xor(bestA, 32);
    float obB = __shfl_xor(bestB, 32);
    int   oiA = __shfl_xor(ia, 32);
    int   oiB = __shfl_xor(ib, 32);
    float loA = half ? obA : bestA,  hiA = half ? bestA : obA;
    int   liA = half ? oiA : ia,     hiiA = half ? ia : oiA;
    int idxA = (loA <= hiA) ? liA : hiiA;
    float loB = half ? obB : bestB,  hiB = half ? bestB : obB;
    int   liB = half ? oiB : ib,     hiiB = half ? ib : oiB;
    int idxB = (loB <= hiB) ? liB : hiiB;

    // f32 update chain (gather from transposed layout; both halves in sync)
#pragma unroll
    for (int d = 0; d < D; ++d) {
      float eA = sCT[d][idxA];
      qvA[d] = qvA[d] + eA;
      rfA[d] = rfA[d] - eA;
      float fA = rfA[d] - eA;
      float eB = sCT[d][idxB];
      qvB[d] = qvB[d] + eB;
      rfB[d] = rfB[d] - eB;
      float fB = rfB[d] - eB;
      if (!half) {
        lossAcc = fma((double)fA, (double)fA, lossAcc);
        lossAcc = fma((double)fB, (double)fB, lossAcc);
      }
    }
    if (!half) {
      out[CODES_OFF + q * TOKENS + t0] = (float)idxA;
      out[CODES_OFF + q * TOKENS + t1] = (float)idxB;
    }
  }

  // straight-through: out_q = f32(x + f32(q - x)) — half 0 writes
  if (!half) {
    const float4* xa = (const float4*)(x + t0 * D);
    const float4* xb = (const float4*)(x + t1 * D);
    float4 a0 = xa[0], a1 = xa[1], b0 = xb[0], b1 = xb[1];
    float xsA[D] = {a0.x, a0.y, a0.z, a0.w, a1.x, a1.y, a1.z, a1.w};
    float xsB[D] = {b0.x, b0.y, b0.z, b0.w, b1.x, b1.y, b1.z, b1.w};
    float oA[D], oB[D];
#pragma unroll
    for (int d = 0; d < D; ++d) {
      oA[d] = xsA[d] + (qvA[d] - xsA[d]);
      oB[d] = xsB[d] + (qvB[d] - xsB[d]);
    }
    float4 v;
    v.x = oA[0]; v.y = oA[1]; v.z = oA[2]; v.w = oA[3];
    ((float4*)(out + t0 * D))[0] = v;
    v.x = oA[4]; v.y = oA[5]; v.z = oA[6]; v.w = oA[7];
    ((float4*)(out + t0 * D))[1] = v;
    v.x = oB[0]; v.y = oB[1]; v.z = oB[2]; v.w = oB[3];
    ((float4*)(out + t1 * D))[0] = v;
    v.x = oB[4]; v.y = oB[5]; v.z = oB[6]; v.w = oB[7];
    ((float4*)(out + t1 * D))[1] = v;
  }

  // block loss reduction (half-1 lanes contribute 0)
  for (int off = 32; off; off >>= 1) lossAcc += __shfl_down(lossAcc, off);
  __syncthreads();
  double* red = (double*)sCT;
  if ((tid & 63) == 0) red[tid >> 6] = lossAcc;
  __syncthreads();
  if (tid == 0) partials[blockIdx.x] = red[0] + red[1] + red[2] + red[3];
}

// ---- finalize loss (GRID=1024 partials) ----
__global__ __launch_bounds__(BLK) void rvq_loss(const double* __restrict__ partials,
                                                float* __restrict__ out) {
  int tid = threadIdx.x;
  double s = partials[tid] + partials[tid + BLK] +
             partials[tid + 2 * BLK] + partials[tid + 3 * BLK];
  for (int off = 32; off; off >>= 1) s += __shfl_down(s, off);
  __shared__ double red[4];
  if ((tid & 63) == 0) red[tid >> 6] = s;
  __syncthreads();
  if (tid == 0)
    out[LOSS_OFF] = (float)((red[0] + red[1] + red[2] + red[3]) *
                            (0.25 / 2097152.0));
}

extern "C" void kernel_launch(void* const* d_in, const int* in_sizes, int n_in,
                              void* d_out, int out_size, void* d_ws, size_t ws_size,
                              hipStream_t stream) {
  const float* x  = (const float*)d_in[0];
  const float* cb = (const float*)d_in[1];
  float* out = (float*)d_out;
  double* partials = (double*)d_ws;          // GRID doubles (8 KiB)
  float* cc = (float*)(partials + GRID);     // Q*K floats (32 KiB)

  rvq_prep<<<(Q * K) / BLK, BLK, 0, stream>>>(cb, cc);
  rvq_main<<<GRID, BLK, 0, stream>>>(x, cb, cc, out, partials);
  rvq_loss<<<1, BLK, 0, stream>>>(partials, out);
}